// Round 13
// baseline (6394.268 us; speedup 1.0000x reference)
//
#include <hip/hip_runtime.h>
#include <hip/hip_bf16.h>

#define DIMS 1024
#define SEQ 512
#define BATCH 128
#define VOCAB 32000
#define GRID 256
#define HDEPTH 32

typedef __attribute__((ext_vector_type(8))) short short8;
typedef __attribute__((ext_vector_type(4))) float f32x4;

__device__ __forceinline__ ushort f2bf(float x) {
    union { float f; unsigned u; } v; v.f = x;
    unsigned u = v.u;
    return (ushort)((u + 0x7FFFu + ((u >> 16) & 1u)) >> 16);
}

// pack 8 consecutive f32 into short8 bf16 via v_cvt_pk_bf16_f32 (RNE, 4 ops)
__device__ __forceinline__ short8 pack8cvt(const float* p) {
    float4 f0 = *(const float4*)p;
    float4 f1 = *(const float4*)(p + 4);
    int r0, r1, r2, r3;
    asm("v_cvt_pk_bf16_f32 %0, %1, %2" : "=v"(r0) : "v"(f0.x), "v"(f0.y));
    asm("v_cvt_pk_bf16_f32 %0, %1, %2" : "=v"(r1) : "v"(f0.z), "v"(f0.w));
    asm("v_cvt_pk_bf16_f32 %0, %1, %2" : "=v"(r2) : "v"(f1.x), "v"(f1.y));
    asm("v_cvt_pk_bf16_f32 %0, %1, %2" : "=v"(r3) : "v"(f1.z), "v"(f1.w));
    union { int i[4]; short8 v; } u;
    u.i[0] = r0; u.i[1] = r1; u.i[2] = r2; u.i[3] = r3;
    return u.v;
}

// Persistent LSTM, fence-free flag sync, R8 homogeneous K-split schedule,
// h transported via depth-32 rotating buffer read with PLAIN cached loads.
// Producers publish h coherently (L3-fresh); consumers' plain reads miss L2
// (slot last cached 32 steps = ~24MB of fills ago -> evicted) and fill from
// L3 once per XCD, then rg-sharing blocks hit L2. Coherent read traffic
// drops 32MB -> ~2MB/step (the measured ~4TB/s coherence ceiling was the
// R3-R10 floor). x@W reads f32 emb + v_cvt_pk_bf16_f32 pack (4 ops/frag).
__launch_bounds__(512, 2)
__global__ void lstm_kernel(const int* __restrict__ feats,
                            const float* __restrict__ emb,
                            const float* __restrict__ Wf, const float* __restrict__ Uf, const float* __restrict__ bfp,
                            const float* __restrict__ Wi, const float* __restrict__ Ui, const float* __restrict__ bip,
                            const float* __restrict__ Wo, const float* __restrict__ Uo, const float* __restrict__ bop,
                            const float* __restrict__ Wc, const float* __restrict__ Uc, const float* __restrict__ bcp,
                            ushort* __restrict__ hrot, float* __restrict__ out, int* __restrict__ flags) {
    __shared__ ushort Bl[32 * 2048];        // 131072 B: B-slice, XOR-swizzled
    __shared__ float pre0[64 * 36];         // K-half 0 partial (x+h), pitch 36
    __shared__ float pre1[64 * 36];         // K-half 1 partial (x+h)

    const int tid = threadIdx.x;
    const int bid = blockIdx.x;
    const int rg = bid >> 7;      // row group: rows rg*64 .. rg*64+63
    const int cb = bid & 127;     // d-chunk: d = cb*8 .. cb*8+7

    // ---- one-time: load B slice (f32 -> bf16) into LDS ----
    for (int idx = tid; idx < 32 * 2048; idx += 512) {
        int cl = idx & 31;
        int k  = idx >> 5;
        int g  = cl >> 3, dd0 = cl & 7;
        int dw = cb * 8 + dd0;
        const float* Wg = (g == 0) ? Wf : (g == 1) ? Wi : (g == 2) ? Wo : Wc;
        const float* Ug = (g == 0) ? Uf : (g == 1) ? Ui : (g == 2) ? Uo : Uc;
        float v = (k < 1024) ? Wg[k * 1024 + dw] : Ug[(k - 1024) * 1024 + dw];
        int boff = ((cl << 12) | (k << 1)) ^ ((cl & 7) << 4);
        *(ushort*)((char*)Bl + boff) = f2bf(v);
    }

    const int lane = tid & 63;
    const int w  = tid >> 6;                 // wave 0..7
    const int wr = w & 3;                    // row quarter: rows wr*16..wr*16+15
    const int kh = w >> 2;                   // K-half: 0 or 1
    const int lx = lane & 15;
    const int qq = lane >> 4;
    const int kg = qq * 8;
    const int lr = wr * 16 + lx;             // local row within row-group
    const int brow = rg * 64 + lr;           // global batch row

    const int bofs0 = (lx << 12) ^ ((lx & 7) << 4);
    const int bofs1 = ((16 + lx) << 12) ^ ((lx & 7) << 4);

    const int kb    = kh * 512;              // K-half base
    const int fbase = kh * 64;               // producer flag/chunk base for h half
    float* myPre = kh ? pre1 : pre0;
    const int r0 = wr * 16 + qq * 4;         // C/D row base (col = lx, row = r0+reg)

    // gate-phase mapping: 1 state per thread: row = tid>>3, dd = tid&7
    const int grow_ = tid >> 3;
    const int gdd   = tid & 7;
    const int gd    = cb * 8 + gdd;
    const float bF = bfp[gd], bI = bip[gd], bO = bop[gd], bC = bcp[gd];

    float cst = 0.f;
    int* myflags = flags + rg * 128;
    int fidx = feats[brow * SEQ];

    __syncthreads();   // Bl ready

    for (int t = 0; t < SEQ; t++) {
        f32x4 a00 = {0,0,0,0}, a01 = {0,0,0,0};   // n-tile 0, even/odd k-step
        f32x4 a10 = {0,0,0,0}, a11 = {0,0,0,0};   // n-tile 1, even/odd k-step

        // ---- x @ W, my K-half (16 k-steps), f32 emb + cvt_pk pack ----
        {
            const float* xrow = emb + (size_t)fidx * DIMS;
            fidx = (t + 1 < SEQ) ? feats[brow * SEQ + t + 1] : 0;
            #pragma unroll 4
            for (int ks = 0; ks < 16; ks += 2) {
                {
                    int k = kb + ks * 32 + kg;
                    short8 a  = pack8cvt(xrow + k);
                    short8 b0 = *(const short8*)((const char*)Bl + (bofs0 ^ (k << 1)));
                    short8 b1 = *(const short8*)((const char*)Bl + (bofs1 ^ (k << 1)));
                    a00 = __builtin_amdgcn_mfma_f32_16x16x32_bf16(a, b0, a00, 0, 0, 0);
                    a10 = __builtin_amdgcn_mfma_f32_16x16x32_bf16(a, b1, a10, 0, 0, 0);
                }
                {
                    int k = kb + (ks + 1) * 32 + kg;
                    short8 a  = pack8cvt(xrow + k);
                    short8 b0 = *(const short8*)((const char*)Bl + (bofs0 ^ (k << 1)));
                    short8 b1 = *(const short8*)((const char*)Bl + (bofs1 ^ (k << 1)));
                    a01 = __builtin_amdgcn_mfma_f32_16x16x32_bf16(a, b0, a01, 0, 0, 0);
                    a11 = __builtin_amdgcn_mfma_f32_16x16x32_bf16(a, b1, a11, 0, 0, 0);
                }
            }
        }

        if (t > 0) {
            // ---- poll my K-half's 64 producers (coherent flags) ----
            long guard = 0;
            for (;;) {
                int f0 = __hip_atomic_load(myflags + fbase + lane, __ATOMIC_RELAXED, __HIP_MEMORY_SCOPE_AGENT);
                if (__all(f0 >= t)) break;
                __builtin_amdgcn_s_sleep(1);
                if (++guard > 100000000L) break;  // deadlock safety valve
            }
            // ---- h @ U, my K-half: PLAIN cached loads from rotation slot ----
            const ushort* hbase = hrot + (size_t)(t % HDEPTH) * (256 * 512) + (size_t)rg * (128 * 512);
            #pragma unroll 4
            for (int ks = 0; ks < 16; ks += 2) {
                {
                    int chunk = fbase + ks * 4 + qq;
                    short8 hv = *(const short8*)(hbase + (chunk << 9) + lr * 8);
                    int k = 1024 + kb + ks * 32 + kg;
                    short8 b0 = *(const short8*)((const char*)Bl + (bofs0 ^ (k << 1)));
                    short8 b1 = *(const short8*)((const char*)Bl + (bofs1 ^ (k << 1)));
                    a00 = __builtin_amdgcn_mfma_f32_16x16x32_bf16(hv, b0, a00, 0, 0, 0);
                    a10 = __builtin_amdgcn_mfma_f32_16x16x32_bf16(hv, b1, a10, 0, 0, 0);
                }
                {
                    int chunk = fbase + (ks + 1) * 4 + qq;
                    short8 hv = *(const short8*)(hbase + (chunk << 9) + lr * 8);
                    int k = 1024 + kb + (ks + 1) * 32 + kg;
                    short8 b0 = *(const short8*)((const char*)Bl + (bofs0 ^ (k << 1)));
                    short8 b1 = *(const short8*)((const char*)Bl + (bofs1 ^ (k << 1)));
                    a01 = __builtin_amdgcn_mfma_f32_16x16x32_bf16(hv, b0, a01, 0, 0, 0);
                    a11 = __builtin_amdgcn_mfma_f32_16x16x32_bf16(hv, b1, a11, 0, 0, 0);
                }
            }
        }

        // ---- write partials (C/D layout: col = lane&15, row = (lane>>4)*4 + reg) ----
        #pragma unroll
        for (int j = 0; j < 4; j++) {
            myPre[(r0 + j) * 36 + lx]      = a00[j] + a01[j];
            myPre[(r0 + j) * 36 + 16 + lx] = a10[j] + a11[j];
        }
        __syncthreads();   // sync A: pre0 + pre1 complete

        // ---- gates: 1 state per thread ----
        {
            int base = grow_ * 36;
            float pf = pre0[base + gdd]      + pre1[base + gdd]      + bF;
            float pi = pre0[base + 8 + gdd]  + pre1[base + 8 + gdd]  + bI;
            float po = pre0[base + 16 + gdd] + pre1[base + 16 + gdd] + bO;
            float pc = pre0[base + 24 + gdd] + pre1[base + 24 + gdd] + bC;
            float f  = 1.f / (1.f + __expf(-pf));
            float ig = 1.f / (1.f + __expf(-pi));
            float o  = 1.f / (1.f + __expf(-po));
            float e2 = __expf(2.f * pc);
            float cc = (e2 - 1.f) / (e2 + 1.f);
            float cn = f * cst + ig * cc;
            cst = cn;
            float e2c = __expf(2.f * cn);
            float th  = (e2c - 1.f) / (e2c + 1.f);
            float h   = o * th;
            if (t < SEQ - 1) {
                // coherent publish: thread tid -> hrot[(t+1)%32][bid][tid]
                ushort* hw = hrot + (size_t)((t + 1) % HDEPTH) * (256 * 512) + (size_t)bid * 512 + tid;
                __hip_atomic_store(hw, f2bf(h), __ATOMIC_RELAXED, __HIP_MEMORY_SCOPE_AGENT);
            } else {
                int gr = rg * 64 + grow_;
                out[gr * 2048 + gd] = h;
                out[gr * 2048 + 1024 + gd] = cn;
            }
        }

        if (t < SEQ - 1) {
            asm volatile("s_waitcnt vmcnt(0)" ::: "memory");  // h stores acked at coherence point
            __syncthreads();                                   // sync B: publishes done; pre[] reusable
            if (tid == 0) {
                __hip_atomic_store(myflags + cb, t + 1, __ATOMIC_RELAXED, __HIP_MEMORY_SCOPE_AGENT);
            }
        }
    }
}

extern "C" void kernel_launch(void* const* d_in, const int* in_sizes, int n_in,
                              void* d_out, int out_size, void* d_ws, size_t ws_size,
                              hipStream_t stream) {
    const int*   feats = (const int*)d_in[0];
    const float* emb_f = (const float*)d_in[1];
    const float* Wf = (const float*)d_in[2];
    const float* Uf = (const float*)d_in[3];
    const float* bf_ = (const float*)d_in[4];
    const float* Wi = (const float*)d_in[5];
    const float* Ui = (const float*)d_in[6];
    const float* bi_ = (const float*)d_in[7];
    const float* Wo = (const float*)d_in[8];
    const float* Uo = (const float*)d_in[9];
    const float* bo_ = (const float*)d_in[10];
    const float* Wc = (const float*)d_in[11];
    const float* Uc = (const float*)d_in[12];
    const float* bc_ = (const float*)d_in[13];

    char* ws = (char*)d_ws;
    ushort* hrot  = (ushort*)ws;                  // [32][256][512] bf16 = 8,388,608 B
    int*    flags = (int*)(ws + 8388608);         // 256 ints
    // total ws use: ~8.4 MB (R11's 70MB layout overran the workspace -> hang)

    hipMemsetAsync(flags, 0, 1024, stream);
    lstm_kernel<<<GRID, 512, 0, stream>>>(feats, emb_f,
                                          Wf, Uf, bf_, Wi, Ui, bi_,
                                          Wo, Uo, bo_, Wc, Uc, bc_,
                                          hrot, (float*)d_out, flags);
}

// Round 14
// 3595.952 us; speedup vs baseline: 1.7782x; 1.7782x over previous
//
#include <hip/hip_runtime.h>
#include <hip/hip_bf16.h>

#define DIMS 1024
#define SEQ 512
#define BATCH 128
#define VOCAB 32000
#define GRID 256

typedef __attribute__((ext_vector_type(8))) short short8;
typedef __attribute__((ext_vector_type(4))) float f32x4;

__device__ __forceinline__ ushort f2bf(float x) {
    union { float f; unsigned u; } v; v.f = x;
    unsigned u = v.u;
    return (ushort)((u + 0x7FFFu + ((u >> 16) & 1u)) >> 16);
}

__global__ void conv_emb_kernel(const float* __restrict__ in, ushort* __restrict__ out, int n) {
    int idx = blockIdx.x * blockDim.x + threadIdx.x;
    int stride = gridDim.x * blockDim.x;
    for (int i = idx * 4; i < n; i += stride * 4) {
        float4 v = *(const float4*)(in + i);
        ushort4 o;
        o.x = f2bf(v.x); o.y = f2bf(v.y); o.z = f2bf(v.z); o.w = f2bf(v.w);
        *(ushort4*)(out + i) = o;
    }
}

// Persistent LSTM, fence-free flag sync, homogeneous K-split waves (R8 shape),
// ONE change vs R8: h-loads are issued as 16 asm volatile global_load_dwordx4
// (sc0 sc1) right after the poll, the x-leg's second half runs during their
// flight, then a single vmcnt(0) + sched_barrier precedes a pure-register
// h-MFMA loop. (R10 tried this with atomic builtins; VGPR 88->96 proved the
// compiler sank the loads to uses — the MLP never materialized. asm pins it.)
// Grid = 256 blocks x 512 threads = 2 row-groups x 128 d-chunks;
// 8 waves = 4 row-quarters x 2 K-halves.
__launch_bounds__(512, 2)
__global__ void lstm_kernel(const int* __restrict__ feats,
                            const ushort* __restrict__ emb,
                            const float* __restrict__ Wf, const float* __restrict__ Uf, const float* __restrict__ bfp,
                            const float* __restrict__ Wi, const float* __restrict__ Ui, const float* __restrict__ bip,
                            const float* __restrict__ Wo, const float* __restrict__ Uo, const float* __restrict__ bop,
                            const float* __restrict__ Wc, const float* __restrict__ Uc, const float* __restrict__ bcp,
                            ushort* __restrict__ hbuf, float* __restrict__ out, int* __restrict__ flags) {
    __shared__ ushort Bl[32 * 2048];        // 131072 B: B-slice, XOR-swizzled
    __shared__ float pre0[64 * 36];         // K-half 0 partial (x+h), pitch 36
    __shared__ float pre1[64 * 36];         // K-half 1 partial (x+h)

    const int tid = threadIdx.x;
    const int bid = blockIdx.x;
    const int rg = bid >> 7;      // row group: rows rg*64 .. rg*64+63
    const int cb = bid & 127;     // d-chunk: d = cb*8 .. cb*8+7

    // ---- one-time: load B slice (f32 -> bf16) into LDS ----
    for (int idx = tid; idx < 32 * 2048; idx += 512) {
        int cl = idx & 31;
        int k  = idx >> 5;
        int g  = cl >> 3, dd0 = cl & 7;
        int dw = cb * 8 + dd0;
        const float* Wg = (g == 0) ? Wf : (g == 1) ? Wi : (g == 2) ? Wo : Wc;
        const float* Ug = (g == 0) ? Uf : (g == 1) ? Ui : (g == 2) ? Uo : Uc;
        float v = (k < 1024) ? Wg[k * 1024 + dw] : Ug[(k - 1024) * 1024 + dw];
        int boff = ((cl << 12) | (k << 1)) ^ ((cl & 7) << 4);
        *(ushort*)((char*)Bl + boff) = f2bf(v);
    }

    const int lane = tid & 63;
    const int w  = tid >> 6;                 // wave 0..7
    const int wr = w & 3;                    // row quarter: rows wr*16..wr*16+15
    const int kh = w >> 2;                   // K-half: 0 or 1
    const int lx = lane & 15;
    const int qq = lane >> 4;
    const int kg = qq * 8;
    const int lr = wr * 16 + lx;             // local row within row-group
    const int brow = rg * 64 + lr;           // global batch row

    const int bofs0 = (lx << 12) ^ ((lx & 7) << 4);
    const int bofs1 = ((16 + lx) << 12) ^ ((lx & 7) << 4);

    const int kb    = kh * 512;              // K-half base
    const int fbase = kh * 64;               // producer flag/chunk base for h half
    float* myPre = kh ? pre1 : pre0;
    const int r0 = wr * 16 + qq * 4;         // C/D row base (col = lx, row = r0+reg)

    // gate-phase mapping: 1 state per thread: row = tid>>3, dd = tid&7
    const int grow_ = tid >> 3;
    const int gdd   = tid & 7;
    const int gd    = cb * 8 + gdd;
    const float bF = bfp[gd], bI = bip[gd], bO = bop[gd], bC = bcp[gd];

    float cst = 0.f;
    int* myflags = flags + rg * 128;
    int fidx = feats[brow * SEQ];

    __syncthreads();   // Bl ready

    for (int t = 0; t < SEQ; t++) {
        f32x4 a00 = {0,0,0,0}, a01 = {0,0,0,0};   // n-tile 0, even/odd k-step
        f32x4 a10 = {0,0,0,0}, a11 = {0,0,0,0};   // n-tile 1, even/odd k-step

        const ushort* xrow = emb + (size_t)fidx * DIMS;
        fidx = (t + 1 < SEQ) ? feats[brow * SEQ + t + 1] : 0;

        // ---- x @ W, my K-half, iters 0..7 (covers flag propagation) ----
        #pragma unroll
        for (int ks = 0; ks < 8; ks += 2) {
            {
                int k = kb + ks * 32 + kg;
                short8 a  = *(const short8*)(xrow + k);
                short8 b0 = *(const short8*)((const char*)Bl + (bofs0 ^ (k << 1)));
                short8 b1 = *(const short8*)((const char*)Bl + (bofs1 ^ (k << 1)));
                a00 = __builtin_amdgcn_mfma_f32_16x16x32_bf16(a, b0, a00, 0, 0, 0);
                a10 = __builtin_amdgcn_mfma_f32_16x16x32_bf16(a, b1, a10, 0, 0, 0);
            }
            {
                int k = kb + (ks + 1) * 32 + kg;
                short8 a  = *(const short8*)(xrow + k);
                short8 b0 = *(const short8*)((const char*)Bl + (bofs0 ^ (k << 1)));
                short8 b1 = *(const short8*)((const char*)Bl + (bofs1 ^ (k << 1)));
                a01 = __builtin_amdgcn_mfma_f32_16x16x32_bf16(a, b0, a01, 0, 0, 0);
                a11 = __builtin_amdgcn_mfma_f32_16x16x32_bf16(a, b1, a11, 0, 0, 0);
            }
        }

        // ---- poll + pinned issue of all 16 h-loads (coherent, batched) ----
        short8 hv[16];
        if (t > 0) {
            long guard = 0;
            for (;;) {
                int f0 = __hip_atomic_load(myflags + fbase + lane, __ATOMIC_RELAXED, __HIP_MEMORY_SCOPE_AGENT);
                if (__all(f0 >= t)) break;
                __builtin_amdgcn_s_sleep(1);
                if (++guard > 100000000L) break;  // deadlock safety valve
            }
            const ushort* hbase = hbuf + (size_t)((t & 1) * 2 + rg) * (128 * 512);
            #pragma unroll
            for (int ks = 0; ks < 16; ks++) {
                const ushort* hp = hbase + ((fbase + ks * 4 + qq) << 9) + lr * 8;
                asm volatile("global_load_dwordx4 %0, %1, off sc0 sc1"
                             : "=v"(hv[ks]) : "v"(hp) : "memory");
            }
        }

        // ---- x @ W, iters 8..15 (hides h-load flight) ----
        #pragma unroll
        for (int ks = 8; ks < 16; ks += 2) {
            {
                int k = kb + ks * 32 + kg;
                short8 a  = *(const short8*)(xrow + k);
                short8 b0 = *(const short8*)((const char*)Bl + (bofs0 ^ (k << 1)));
                short8 b1 = *(const short8*)((const char*)Bl + (bofs1 ^ (k << 1)));
                a00 = __builtin_amdgcn_mfma_f32_16x16x32_bf16(a, b0, a00, 0, 0, 0);
                a10 = __builtin_amdgcn_mfma_f32_16x16x32_bf16(a, b1, a10, 0, 0, 0);
            }
            {
                int k = kb + (ks + 1) * 32 + kg;
                short8 a  = *(const short8*)(xrow + k);
                short8 b0 = *(const short8*)((const char*)Bl + (bofs0 ^ (k << 1)));
                short8 b1 = *(const short8*)((const char*)Bl + (bofs1 ^ (k << 1)));
                a01 = __builtin_amdgcn_mfma_f32_16x16x32_bf16(a, b0, a01, 0, 0, 0);
                a11 = __builtin_amdgcn_mfma_f32_16x16x32_bf16(a, b1, a11, 0, 0, 0);
            }
        }

        // ---- h @ U MFMA loop: wait once, then registers + LDS only ----
        if (t > 0) {
            asm volatile("s_waitcnt vmcnt(0)" ::: "memory");
            __builtin_amdgcn_sched_barrier(0);   // rule #18: pin MFMAs below the wait
            #pragma unroll
            for (int ks = 0; ks < 16; ks += 2) {
                {
                    int k = 1024 + kb + ks * 32 + kg;
                    short8 b0 = *(const short8*)((const char*)Bl + (bofs0 ^ (k << 1)));
                    short8 b1 = *(const short8*)((const char*)Bl + (bofs1 ^ (k << 1)));
                    a00 = __builtin_amdgcn_mfma_f32_16x16x32_bf16(hv[ks], b0, a00, 0, 0, 0);
                    a10 = __builtin_amdgcn_mfma_f32_16x16x32_bf16(hv[ks], b1, a10, 0, 0, 0);
                }
                {
                    int k = 1024 + kb + (ks + 1) * 32 + kg;
                    short8 b0 = *(const short8*)((const char*)Bl + (bofs0 ^ (k << 1)));
                    short8 b1 = *(const short8*)((const char*)Bl + (bofs1 ^ (k << 1)));
                    a01 = __builtin_amdgcn_mfma_f32_16x16x32_bf16(hv[ks + 1], b0, a01, 0, 0, 0);
                    a11 = __builtin_amdgcn_mfma_f32_16x16x32_bf16(hv[ks + 1], b1, a11, 0, 0, 0);
                }
            }
        }

        // ---- write partials (C/D layout: col = lane&15, row = (lane>>4)*4 + reg) ----
        #pragma unroll
        for (int j = 0; j < 4; j++) {
            myPre[(r0 + j) * 36 + lx]      = a00[j] + a01[j];
            myPre[(r0 + j) * 36 + 16 + lx] = a10[j] + a11[j];
        }
        __syncthreads();   // sync A: pre0 + pre1 complete

        // ---- gates: 1 state per thread ----
        {
            int base = grow_ * 36;
            float pf = pre0[base + gdd]      + pre1[base + gdd]      + bF;
            float pi = pre0[base + 8 + gdd]  + pre1[base + 8 + gdd]  + bI;
            float po = pre0[base + 16 + gdd] + pre1[base + 16 + gdd] + bO;
            float pc = pre0[base + 24 + gdd] + pre1[base + 24 + gdd] + bC;
            float f  = 1.f / (1.f + __expf(-pf));
            float ig = 1.f / (1.f + __expf(-pi));
            float o  = 1.f / (1.f + __expf(-po));
            float e2 = __expf(2.f * pc);
            float cc = (e2 - 1.f) / (e2 + 1.f);
            float cn = f * cst + ig * cc;
            cst = cn;
            float e2c = __expf(2.f * cn);
            float th  = (e2c - 1.f) / (e2c + 1.f);
            float h   = o * th;
            if (t < SEQ - 1) {
                // coalesced publish: thread tid -> hnext[cb*512 + tid]
                ushort* hw = hbuf + (size_t)(((t + 1) & 1) * 2 + rg) * (128 * 512) + cb * 512 + tid;
                __hip_atomic_store(hw, f2bf(h), __ATOMIC_RELAXED, __HIP_MEMORY_SCOPE_AGENT);
            } else {
                int gr = rg * 64 + grow_;
                out[gr * 2048 + gd] = h;
                out[gr * 2048 + 1024 + gd] = cn;
            }
        }

        if (t < SEQ - 1) {
            asm volatile("s_waitcnt vmcnt(0)" ::: "memory");  // h stores acked at coherence point
            __syncthreads();                                   // sync B: publishes done; pre[] reusable
            if (tid == 0) {
                __hip_atomic_store(myflags + cb, t + 1, __ATOMIC_RELAXED, __HIP_MEMORY_SCOPE_AGENT);
            }
        }
    }
}

extern "C" void kernel_launch(void* const* d_in, const int* in_sizes, int n_in,
                              void* d_out, int out_size, void* d_ws, size_t ws_size,
                              hipStream_t stream) {
    const int*   feats = (const int*)d_in[0];
    const float* emb_f = (const float*)d_in[1];
    const float* Wf = (const float*)d_in[2];
    const float* Uf = (const float*)d_in[3];
    const float* bf_ = (const float*)d_in[4];
    const float* Wi = (const float*)d_in[5];
    const float* Ui = (const float*)d_in[6];
    const float* bi_ = (const float*)d_in[7];
    const float* Wo = (const float*)d_in[8];
    const float* Uo = (const float*)d_in[9];
    const float* bo_ = (const float*)d_in[10];
    const float* Wc = (const float*)d_in[11];
    const float* Uc = (const float*)d_in[12];
    const float* bc_ = (const float*)d_in[13];

    char* ws = (char*)d_ws;
    ushort* emb_bf = (ushort*)ws;                          // 65,536,000 B
    ushort* hbuf   = (ushort*)(ws + 65536000);             // 2x2x128x64x8 bf16 = 524,288 B
    int*    flags  = (int*)(ws + 65536000 + 524288);       // 256 flags

    hipMemsetAsync(flags, 0, 1024, stream);
    conv_emb_kernel<<<1024, 256, 0, stream>>>(emb_f, emb_bf, VOCAB * DIMS);
    lstm_kernel<<<GRID, 512, 0, stream>>>(feats, emb_bf,
                                          Wf, Uf, bf_, Wi, Ui, bi_,
                                          Wo, Uo, bo_, Wc, Uc, bc_,
                                          hbuf, (float*)d_out, flags);
}